// Round 2
// 310.221 us; speedup vs baseline: 1.0449x; 1.0449x over previous
//
#include <hip/hip_runtime.h>
#include <hip/hip_bf16.h>
#include <cstdint>
#include <cstddef>

typedef unsigned short ushort_t;
typedef __attribute__((ext_vector_type(8))) short short8;     // 8 bf16 = 4 VGPRs (MFMA A/B frag)
typedef __attribute__((ext_vector_type(8))) unsigned short ushort8;
typedef __attribute__((ext_vector_type(4))) unsigned short ushort4v;
typedef __attribute__((ext_vector_type(4))) float f32x4;
typedef __attribute__((ext_vector_type(2))) unsigned long long ull2;
typedef __attribute__((ext_vector_type(2))) unsigned int uint2v;

// Problem constants: B=2, L=2048, DIM=1024, H=16, dk=64
#define LPAD 72   // flash P LDS row stride (u16)

__device__ __forceinline__ unsigned short f2bf(float f) {
    unsigned int x = __float_as_uint(f);
    unsigned int r = x + 0x7fffu + ((x >> 16) & 1u);   // RNE
    return (unsigned short)(r >> 16);
}

__device__ __forceinline__ unsigned int cvt_pk_bf16(float lo, float hi) {
    unsigned int r;
    asm("v_cvt_pk_bf16_f32 %0, %1, %2" : "=v"(r) : "v"(lo), "v"(hi));
    return r;
}

// async global->LDS, 16 B per lane. LDS dest = wave-uniform base + lane*16 (m104 caveat).
__device__ __forceinline__ void async16(const ushort_t* g, ushort_t* l) {
    __builtin_amdgcn_global_load_lds(
        (const __attribute__((address_space(1))) unsigned int*)g,
        (__attribute__((address_space(3))) unsigned int*)l,
        16, 0, 0);
}

// fp32 -> bf16 pre-convert. z=0: q (scaled 1/8, exact), z=1: k, z=2: v; plus its weight.
__global__ __launch_bounds__(256) void cvt(const float* __restrict__ q,
                                           const float* __restrict__ k,
                                           const float* __restrict__ v,
                                           const float* __restrict__ Wq,
                                           const float* __restrict__ Wk,
                                           const float* __restrict__ Wv,
                                           ushort_t* __restrict__ qb,
                                           ushort_t* __restrict__ kb,
                                           ushort_t* __restrict__ vb,
                                           ushort_t* __restrict__ Wqb,
                                           ushort_t* __restrict__ Wkb,
                                           ushort_t* __restrict__ Wvb) {
    const int z = blockIdx.y;
    const float* X = (z == 0) ? q : (z == 1) ? k : v;
    const float* W = (z == 0) ? Wq : (z == 1) ? Wk : Wv;
    ushort_t* Xo = (z == 0) ? qb : (z == 1) ? kb : vb;
    ushort_t* Wo2 = (z == 0) ? Wqb : (z == 1) ? Wkb : Wvb;
    const size_t idx = (((size_t)blockIdx.x << 8) + threadIdx.x) << 3;
    const float* src; ushort_t* dst; float sc = 1.0f;
    if (idx < 4194304) { src = X + idx; dst = Xo + idx; if (z == 0) sc = 0.125f; }
    else               { src = W + (idx - 4194304); dst = Wo2 + (idx - 4194304); }
    f32x4 a0 = *(const f32x4*)src, a1 = *(const f32x4*)(src + 4);
    ushort8 o;
    #pragma unroll
    for (int j = 0; j < 4; j++) { o[j] = f2bf(a0[j] * sc); o[j + 4] = f2bf(a1[j] * sc); }
    *(ushort8*)dst = o;
}

// Pack mask (int32, nonzero = masked) into bits, tile-major:
// Mbits[(o/64)*4096 + (b*2048+i)] bit (o%64).
__global__ __launch_bounds__(256) void maskbits_kernel(const int* __restrict__ mask,
                                                       unsigned long long* __restrict__ Mbits) {
    const int row  = blockIdx.x;               // b*2048 + i
    const int w    = threadIdx.x >> 6;
    const int lane = threadIdx.x & 63;
    const int* mrow = mask + (size_t)row * 2048;
    #pragma unroll
    for (int it = 0; it < 8; it++) {
        const int o = (it << 8) + (w << 6) + lane;
        const unsigned long long bb = __ballot(mrow[o] != 0);
        if (lane == 0) Mbits[(size_t)((it << 2) + w) * 4096 + row] = bb;
    }
}

// WoH[j][k] = bf16(Wo[j][(k&63)*16 + (k>>6)]), k = h*64+d ordering.
__global__ __launch_bounds__(256) void woswz(const float* __restrict__ W,
                                             ushort_t* __restrict__ WoH) {
    __shared__ float row[1024 + 64];
    const int j = blockIdx.x, t = threadIdx.x;
    f32x4 v = *(const f32x4*)(W + (size_t)j * 1024 + (t << 2));
    #pragma unroll
    for (int s = 0; s < 4; s++) { const int c = (t << 2) + s; row[c + (c >> 4)] = v[s]; }
    __syncthreads();
    #pragma unroll
    for (int s = 0; s < 4; s++) {
        const int k = t + (s << 8);
        const int col = ((k & 63) << 4) + (k >> 6);
        WoH[(size_t)j * 1024 + k] = f2bf(row[col + (col >> 4)]);
    }
}

// Fused QKV projection, 128x128 tile, BK=32, global_load_lds staging.
// 1-D grid 768, decoded so all 8 n-blocks of (z,m) share one XCD (lid%8 == m%8):
// co-resident writers fully dirty each output L2 line -> no writeback amplification.
// LDS layout [c4][row][8] (unpadded, matches async lane order; frag reads 2-way/free).
// z=0: Qh[bh][l][d]; z=1: Kh[bh][l][d]; z=2: VhT[bh][d][l]. Direct b64 stores.
__global__ __launch_bounds__(256) void gemm_proj(const ushort_t* __restrict__ qb,
                                                 const ushort_t* __restrict__ kb,
                                                 const ushort_t* __restrict__ vb,
                                                 const ushort_t* __restrict__ Wqb,
                                                 const ushort_t* __restrict__ Wkb,
                                                 const ushort_t* __restrict__ Wvb,
                                                 ushort_t* __restrict__ Qh,
                                                 ushort_t* __restrict__ Kh,
                                                 ushort_t* __restrict__ VhT) {
    __shared__ ushort_t Xs[512 * 8];   // 8 KB: [c4][128 rows][8]
    __shared__ ushort_t Ws[512 * 8];   // 8 KB

    const int lid  = blockIdx.x;       // 0..767
    const int nIdx = lid / 96;         // 0..7
    const int rem  = lid % 96;
    const int z    = rem >> 5;         // 0..2
    const int mIdx = rem & 31;         // 0..31
    const int n0   = nIdx << 7;
    const int m0   = mIdx << 7;

    const ushort_t* Xb = (z == 0) ? qb : (z == 1) ? kb : vb;
    const ushort_t* Wb = (z == 0) ? Wqb : (z == 1) ? Wkb : Wvb;

    const int tid  = threadIdx.x;
    const int w    = tid >> 6;
    const int lane = tid & 63;
    const int lm   = lane & 15;
    const int quad = lane >> 4;
    const int wm   = w & 1;            // M half
    const int wn   = w >> 1;           // N half

    f32x4 acc[4][4];
    #pragma unroll
    for (int i = 0; i < 4; i++)
        #pragma unroll
        for (int j = 0; j < 4; j++) acc[i][j] = (f32x4){0.f, 0.f, 0.f, 0.f};

    for (int k0 = 0; k0 < 1024; k0 += 32) {
        __syncthreads();
        #pragma unroll
        for (int i = 0; i < 2; i++) {
            const int L   = (((w << 1) + i) << 6) + lane;   // 0..511
            const int c4  = L >> 7, row = L & 127;
            const int lb  = (((w << 1) + i) << 6) << 3;     // wave-uniform LDS base (u16)
            async16(Xb + (size_t)(m0 + row) * 1024 + k0 + (c4 << 3), &Xs[lb]);
            async16(Wb + (size_t)(n0 + row) * 1024 + k0 + (c4 << 3), &Ws[lb]);
        }
        __syncthreads();
        short8 af[4], bf4[4];
        #pragma unroll
        for (int mf = 0; mf < 4; mf++)
            af[mf] = *(const short8*)&Xs[((quad << 7) + (wm << 6) + (mf << 4) + lm) << 3];
        #pragma unroll
        for (int nf = 0; nf < 4; nf++)
            bf4[nf] = *(const short8*)&Ws[((quad << 7) + (wn << 6) + (nf << 4) + lm) << 3];
        #pragma unroll
        for (int mf = 0; mf < 4; mf++)
            #pragma unroll
            for (int nf = 0; nf < 4; nf++)
                acc[mf][nf] = __builtin_amdgcn_mfma_f32_16x16x32_bf16(af[mf], bf4[nf], acc[mf][nf], 0, 0, 0);
    }

    // Direct stores. col = n0 + wn*64 + nf*16 + lm -> h = lm, d = 8*nIdx + 4*wn + nf.
    const int bb    = m0 >> 11;
    const int l0    = m0 & 2047;
    const int dbase = (n0 >> 4) + (wn << 2);
    if (z != 2) {
        ushort_t* OUT = (z == 0) ? Qh : Kh;
        #pragma unroll
        for (int mf = 0; mf < 4; mf++)
            #pragma unroll
            for (int r = 0; r < 4; r++) {
                const int row = (wm << 6) + (mf << 4) + (quad << 2) + r;
                ushort4v o = { f2bf(acc[mf][0][r]), f2bf(acc[mf][1][r]),
                               f2bf(acc[mf][2][r]), f2bf(acc[mf][3][r]) };
                *(ushort4v*)(OUT + ((size_t)((bb << 4) + lm) * 2048 + l0 + row) * 64 + dbase) = o;
            }
    } else {
        #pragma unroll
        for (int mf = 0; mf < 4; mf++)
            #pragma unroll
            for (int nf = 0; nf < 4; nf++) {
                const int lbase = l0 + (wm << 6) + (mf << 4) + (quad << 2);
                ushort4v o = { f2bf(acc[mf][nf][0]), f2bf(acc[mf][nf][1]),
                               f2bf(acc[mf][nf][2]), f2bf(acc[mf][nf][3]) };
                *(ushort4v*)(VhT + ((size_t)((bb << 4) + lm) * 64 + dbase + nf) * 2048 + lbase) = o;
            }
    }
}

// Output GEMM, 128x64 tile, BK=32, global_load_lds staging, 512 blocks (2/CU).
// XCD-grouped m-panels: xcd = lid%8 owns m in {4k..4k+3}.
__global__ __launch_bounds__(256) void gemm_out(const ushort_t* __restrict__ mhaH,
                                                const ushort_t* __restrict__ WoH,
                                                float* __restrict__ C) {
    __shared__ ushort_t Xs[512 * 8];   // [c4][128 rows][8] 8KB
    __shared__ ushort_t Ws[256 * 8];   // [c4][64 rows][8] 4KB

    const int lid  = blockIdx.x;       // 0..511
    const int mIdx = ((lid & 7) << 2) | ((lid >> 3) & 3);   // 0..31
    const int nIdx = lid >> 5;                               // 0..15
    const int m0   = mIdx << 7;
    const int n0   = nIdx << 6;

    const int tid  = threadIdx.x;
    const int w    = tid >> 6;
    const int lane = tid & 63;
    const int lm   = lane & 15;
    const int quad = lane >> 4;
    const int wm   = w & 1;            // M half (64 rows)
    const int wn   = w >> 1;           // N half (32 cols)
    const int ab   = m0 >> 11;
    const int al0  = m0 & 2047;

    f32x4 acc[4][2];
    #pragma unroll
    for (int i = 0; i < 4; i++)
        #pragma unroll
        for (int j = 0; j < 2; j++) acc[i][j] = (f32x4){0.f, 0.f, 0.f, 0.f};

    for (int k0 = 0; k0 < 1024; k0 += 32) {
        const int h  = k0 >> 6;
        const int d0 = k0 & 63;
        __syncthreads();
        #pragma unroll
        for (int i = 0; i < 2; i++) {
            const int L   = (i << 8) + (w << 6) + lane;     // 0..511
            const int c4  = L >> 7, row = L & 127;
            async16(mhaH + ((size_t)(ab * 16 + h) * 2048 + al0 + row) * 64 + d0 + (c4 << 3),
                    &Xs[((i << 8) + (w << 6)) << 3]);
        }
        {
            const int L   = (w << 6) + lane;                // 0..255
            const int c4  = L >> 6, row = L & 63;
            async16(WoH + (size_t)(n0 + row) * 1024 + k0 + (c4 << 3),
                    &Ws[(w << 6) << 3]);
        }
        __syncthreads();
        short8 af[4], bf2[2];
        #pragma unroll
        for (int mf = 0; mf < 4; mf++)
            af[mf] = *(const short8*)&Xs[((quad << 7) + (wm << 6) + (mf << 4) + lm) << 3];
        #pragma unroll
        for (int nf = 0; nf < 2; nf++)
            bf2[nf] = *(const short8*)&Ws[((quad << 6) + (wn << 5) + (nf << 4) + lm) << 3];
        #pragma unroll
        for (int mf = 0; mf < 4; mf++)
            #pragma unroll
            for (int nf = 0; nf < 2; nf++)
                acc[mf][nf] = __builtin_amdgcn_mfma_f32_16x16x32_bf16(af[mf], bf2[nf], acc[mf][nf], 0, 0, 0);
    }
    #pragma unroll
    for (int mf = 0; mf < 4; mf++)
        #pragma unroll
        for (int nf = 0; nf < 2; nf++)
            #pragma unroll
            for (int r = 0; r < 4; r++) {
                const int row = m0 + (wm << 6) + (mf << 4) + (quad << 2) + r;
                const int col = n0 + (wn << 5) + (nf << 4) + lm;
                C[(size_t)row * 1024 + col] = acc[mf][nf][r];
            }
}

// MFMA flash attention v5: v3's deterministic 2-barrier LDS-staged skeleton +
// fragment-order K/V staging via global_load_lds (per-lane global src carries the
// permutation, LDS dest is linear: chunk (c*2+half)*64 + lane -> every frag
// ds_read_b128 is lane-linear = conflict-free) + interleaved key map
// (B-frag col lm <-> key 4*lm+c) enabling packed softmax: nibble mask decode +
// 2x v_cvt_pk_bf16_f32 + one b64 P-write per q-row (replaces 4 f2bf + 4 b16 stores).
// Grid 512 1-D, XCD-grouped bh (K+V+Q+mask ~3.5MB per XCD L2).
__global__ __launch_bounds__(256, 2) void flash_attn(const ushort_t* __restrict__ Qh,
                                                     const ushort_t* __restrict__ Kh,
                                                     const ushort_t* __restrict__ VhT,
                                                     const unsigned long long* __restrict__ Mbits,
                                                     ushort_t* __restrict__ mhaH) {
    __shared__ ushort_t Ks[512 * 8];         // 8KB fragment-order K tile
    __shared__ ushort_t Vs[512 * 8];         // 8KB fragment-order V^T tile
    __shared__ ushort_t Pw[4][16 * LPAD];    // per-wave P [qrow16][key64], padded

    const int tid  = threadIdx.x;
    const int w    = tid >> 6;
    const int lane = tid & 63;
    const int lm   = lane & 15;
    const int quad = lane >> 4;
    const int lid  = blockIdx.x;             // 0..511
    const int bh   = ((lid & 7) << 2) | ((lid >> 3) & 3);   // 0..31, XCD-grouped
    const int q0   = (lid >> 5) << 7;        // 0..1920
    const int b    = bh >> 4;

    const ushort_t* Qb  = Qh  + ((size_t)bh << 17);
    const ushort_t* Kb  = Kh  + ((size_t)bh << 17);
    const ushort_t* Vtb = VhT + ((size_t)bh << 17);   // [d][l]

    short8 aq[2][2];
    #pragma unroll
    for (int g = 0; g < 2; g++) {
        const ushort_t* qp = Qb + (size_t)(q0 + (w << 5) + (g << 4) + lm) * 64 + (quad << 3);
        aq[g][0] = *(const short8*)qp;
        aq[g][1] = *(const short8*)(qp + 32);
    }

    float l_part[2][4] = {{0.f,0.f,0.f,0.f},{0.f,0.f,0.f,0.f}};
    f32x4 o_acc[2][4] = {{{0.f,0.f,0.f,0.f},{0.f,0.f,0.f,0.f},{0.f,0.f,0.f,0.f},{0.f,0.f,0.f,0.f}},
                         {{0.f,0.f,0.f,0.f},{0.f,0.f,0.f,0.f},{0.f,0.f,0.f,0.f},{0.f,0.f,0.f,0.f}}};

    const int rowbase  = (b << 11) + q0 + (w << 5);
    const int shamt    = (lm & 7) << 2;
    const bool hi_half = lm >= 8;

    // staging: wave w stages K group c=w (both halves) and V group cd=w.
    // per-lane global source: K row 4*lm + w, col quad*8 (+32 for half 1);
    //                         V^T row d = w*16+lm, key col quad*8 (+32).
    const ushort_t* ksrc = Kb  + (size_t)((lm << 2) + w) * 64 + (quad << 3);
    const ushort_t* vsrc = Vtb + (size_t)((w << 4) + lm) * 2048 + (quad << 3);
    ushort_t* kdst0 = &Ks[((w << 7)     ) << 3];   // chunk base (w*2+0)*64
    ushort_t* kdst1 = &Ks[((w << 7) + 64) << 3];   // chunk base (w*2+1)*64
    ushort_t* vdst0 = &Vs[((w << 7)     ) << 3];
    ushort_t* vdst1 = &Vs[((w << 7) + 64) << 3];

    for (int kt0 = 0; kt0 < 2048; kt0 += 64) {
        __syncthreads();
        async16(ksrc + (size_t)kt0 * 64,      kdst0);
        async16(ksrc + (size_t)kt0 * 64 + 32, kdst1);
        async16(vsrc + kt0,      vdst0);
        async16(vsrc + kt0 + 32, vdst1);
        __syncthreads();   // drains vmcnt -> staged data visible to all waves

        // fragment reads: lane-linear, conflict-free
        short8 bk[4][2], bv[4][2];
        #pragma unroll
        for (int c = 0; c < 4; c++) {
            bk[c][0] = *(const short8*)&Ks[((c << 7) + lane) << 3];
            bk[c][1] = *(const short8*)&Ks[((c << 7) + 64 + lane) << 3];
            bv[c][0] = *(const short8*)&Vs[((c << 7) + lane) << 3];
            bv[c][1] = *(const short8*)&Vs[((c << 7) + 64 + lane) << 3];
        }

        const unsigned long long* Mt = Mbits + (size_t)(kt0 >> 6) * 4096 + rowbase;

        #pragma unroll
        for (int g = 0; g < 2; g++) {
            // QK^T: S col lm of block c <-> key 4*lm + c
            f32x4 s[4];
            #pragma unroll
            for (int c = 0; c < 4; c++) {
                f32x4 zz = {0.f, 0.f, 0.f, 0.f};
                zz = __builtin_amdgcn_mfma_f32_16x16x32_bf16(aq[g][0], bk[c][0], zz, 0, 0, 0);
                zz = __builtin_amdgcn_mfma_f32_16x16x32_bf16(aq[g][1], bk[c][1], zz, 0, 0, 0);
                s[c] = zz;
            }
            unsigned long long mb[4];
            {
                const unsigned long long* mp = Mt + (g << 4) + (quad << 2);
                ull2 t0 = *(const ull2*)mp;
                ull2 t1 = *(const ull2*)(mp + 2);
                mb[0] = t0[0]; mb[1] = t0[1]; mb[2] = t1[0]; mb[3] = t1[1];
            }
            #pragma unroll
            for (int r = 0; r < 4; r++) {
                const unsigned long long m64 = mb[r];
                const unsigned word = hi_half ? (unsigned)(m64 >> 32) : (unsigned)m64;
                const unsigned nib  = (word >> shamt) & 0xFu;   // bits for keys 4lm..4lm+3
                float p0 = __expf(s[0][r]); if (nib & 1u) p0 = 0.f;
                float p1 = __expf(s[1][r]); if (nib & 2u) p1 = 0.f;
                float p2 = __expf(s[2][r]); if (nib & 4u) p2 = 0.f;
                float p3 = __expf(s[3][r]); if (nib & 8u) p3 = 0.f;
                l_part[g][r] += (p0 + p1) + (p2 + p3);
                uint2v pv2;
                pv2[0] = cvt_pk_bf16(p0, p1);
                pv2[1] = cvt_pk_bf16(p2, p3);
                *(uint2v*)&Pw[w][((quad << 2) + r) * LPAD + (lm << 2)] = pv2;
            }
            short8 ap0 = *(const short8*)&Pw[w][lm * LPAD + (quad << 3)];
            short8 ap1 = *(const short8*)&Pw[w][lm * LPAD + 32 + (quad << 3)];
            #pragma unroll
            for (int cd = 0; cd < 4; cd++) {
                o_acc[g][cd] = __builtin_amdgcn_mfma_f32_16x16x32_bf16(ap0, bv[cd][0], o_acc[g][cd], 0, 0, 0);
                o_acc[g][cd] = __builtin_amdgcn_mfma_f32_16x16x32_bf16(ap1, bv[cd][1], o_acc[g][cd], 0, 0, 0);
            }
        }
    }

    #pragma unroll
    for (int g = 0; g < 2; g++) {
        #pragma unroll
        for (int r = 0; r < 4; r++) {
            float l = l_part[g][r];
            l += __shfl_xor(l, 1, 64);
            l += __shfl_xor(l, 2, 64);
            l += __shfl_xor(l, 4, 64);
            l += __shfl_xor(l, 8, 64);
            const float inv_l = 1.0f / l;
            const int i = q0 + (w << 5) + (g << 4) + (quad << 2) + r;
            ushort_t* orow = mhaH + (((size_t)bh * 2048 + i) << 6);
            #pragma unroll
            for (int cd = 0; cd < 4; cd++)
                orow[(cd << 4) + lm] = f2bf(o_acc[g][cd][r] * inv_l);
        }
    }
}

extern "C" void kernel_launch(void* const* d_in, const int* in_sizes, int n_in,
                              void* d_out, int out_size, void* d_ws, size_t ws_size,
                              hipStream_t stream) {
    const float* q    = (const float*)d_in[0];
    const float* k    = (const float*)d_in[1];
    const float* v    = (const float*)d_in[2];
    const int*   mask = (const int*)d_in[3];
    const float* Wq   = (const float*)d_in[4];
    const float* Wk   = (const float*)d_in[5];
    const float* Wv   = (const float*)d_in[6];
    const float* Wo   = (const float*)d_in[7];
    float* out = (float*)d_out;

    // ws plan (u16 units): qb kb vb (4M) | Wqb Wkb Wvb (1M) | Qh Kh VhT (4M) = 27M u16 = 54 MB
    // mhaH aliases qb; WoH + Mbits alias kb (both dead after gemm_proj).
    ushort_t* qb   = (ushort_t*)d_ws;
    ushort_t* kb   = qb  + 4194304;
    ushort_t* vb   = kb  + 4194304;
    ushort_t* Wqb  = vb  + 4194304;
    ushort_t* Wkb  = Wqb + 1048576;
    ushort_t* Wvb  = Wkb + 1048576;
    ushort_t* Qh   = Wvb + 1048576;
    ushort_t* Kh   = Qh  + 4194304;
    ushort_t* VhT  = Kh  + 4194304;
    ushort_t* mhaH = qb;
    ushort_t* WoH  = kb;
    unsigned long long* Mbits = (unsigned long long*)(kb + 1048576);

    dim3 gb(256);
    cvt<<<dim3(2560, 3), gb, 0, stream>>>(q, k, v, Wq, Wk, Wv, qb, kb, vb, Wqb, Wkb, Wvb);
    gemm_proj<<<dim3(768), gb, 0, stream>>>(qb, kb, vb, Wqb, Wkb, Wvb, Qh, Kh, VhT);
    maskbits_kernel<<<dim3(4096), gb, 0, stream>>>(mask, Mbits);
    woswz<<<dim3(1024), gb, 0, stream>>>(Wo, WoH);
    flash_attn<<<dim3(512), gb, 0, stream>>>(Qh, Kh, VhT, Mbits, mhaH);
    gemm_out<<<dim3(512), gb, 0, stream>>>(mhaH, WoH, out);
}